// Round 7
// baseline (93.285 us; speedup 1.0000x reference)
//
#include <hip/hip_runtime.h>
#include <hip/hip_bf16.h>

#define HIDDEN 14336

// Fixed 28x28 Hadamard sign matrix from the reference (row-major, '+' = +1).
// Structure (verified R2): H28 = [[C+I, C-I],[C-I, -(C+I)]], C = 14x14
// zero-diag conference matrix, C[i][j] = HS[i][j] for i,j<14, i!=j.
constexpr char HS[28][29] = {
    "++++++++++++++-+++++++++++++",
    "+++-++----++-++-+-++----++-+",
    "++++-++----++-++-+-++----++-",
    "+-+++-++----+++-+-+-++----++",
    "++-+++-++----+++-+-+-++----+",
    "+++-+++-++----+++-+-+-++----",
    "+-++-+++-++---+-++-+-+-++---",
    "+--++-+++-++--+--++-+-+-++--",
    "+---++-+++-++-+---++-+-+-++-",
    "+----++-+++-+++----++-+-+-++",
    "++----++-+++-+++----++-+-+-+",
    "+++----++-+++-+++----++-+-+-",
    "+-++----++-++++-++----++-+-+",
    "++-++----++-++++-++----++-+-",
    "-+++++++++++++--------------",
    "+-+-++----++-+---+--++++--+-",
    "++-+-++----++-----+--++++--+",
    "+-+-+-++----++-+---+--++++--",
    "++-+-+-++----+--+---+--++++-",
    "+++-+-+-++-------+---+--++++",
    "+-++-+-+-++----+--+---+--+++",
    "+--++-+-+-++---++--+---+--++",
    "+---++-+-+-++--+++--+---+--+",
    "+----++-+-+-++-++++--+---+--",
    "++----++-+-+-+--++++--+---+-",
    "+++----++-+-+----++++--+---+",
    "+-++----++-+-+-+--++++--+---",
    "++-++----++-+---+--++++--+--",
};

// 4-point FWHT on 4 register refs.
static __device__ __forceinline__ void fwht4(float& a, float& b, float& c, float& d) {
    const float t0 = a + b, t1 = a - b, t2 = c + d, t3 = c - d;
    a = t0 + t2; b = t1 + t3; c = t0 - t2; d = t1 - t3;
}

// Cross-lane butterfly: out_l = v_{l^m} + sgn_l * v_l, sgn in a VGPR (+-1.0).
// XOR-1 / XOR-2 partners via DPP quad_perm (VALU pipe).
template <int CTRL>
static __device__ __forceinline__ float bfly_dpp(float x, float sgn) {
    const int fi = __float_as_int(x);
    const int p = __builtin_amdgcn_update_dpp(fi, fi, CTRL, 0xF, 0xF, false);
    return fmaf(sgn, x, __int_as_float(p));
}

// XOR-4 / 8 / 16 partners via ds_swizzle BitMode (intra-32-lane).
template <int PAT>
static __device__ __forceinline__ float bfly_swz(float x, float sgn) {
    const int p = __builtin_amdgcn_ds_swizzle(__float_as_int(x), PAT);
    return fmaf(sgn, x, __int_as_float(p));
}

// Full FWHT-512 on one chunk held as v[r_hi*4 + r_lo], element
// i = r_hi*128 + q*4 + r_lo  (q = lane within 32-lane half-wave).
static __device__ __forceinline__ void fwht512(float (&v)[16], float s1, float s2,
                                               float s4, float s8, float s16) {
    // bits b0,b1 (r_lo) within each r_hi group
    #pragma unroll
    for (int g = 0; g < 4; ++g) fwht4(v[4 * g + 0], v[4 * g + 1], v[4 * g + 2], v[4 * g + 3]);
    // bits b2..b6 across lanes
    #pragma unroll
    for (int k = 0; k < 16; ++k) v[k] = bfly_dpp<0xB1>(v[k], s1);   // quad_perm [1,0,3,2]
    #pragma unroll
    for (int k = 0; k < 16; ++k) v[k] = bfly_dpp<0x4E>(v[k], s2);   // quad_perm [2,3,0,1]
    #pragma unroll
    for (int k = 0; k < 16; ++k) v[k] = bfly_swz<0x101F>(v[k], s4);  // lane xor 4
    #pragma unroll
    for (int k = 0; k < 16; ++k) v[k] = bfly_swz<0x201F>(v[k], s8);  // lane xor 8
    #pragma unroll
    for (int k = 0; k < 16; ++k) v[k] = bfly_swz<0x401F>(v[k], s16); // lane xor 16
    // bits b7,b8 (r_hi) at each r_lo position
    #pragma unroll
    for (int e = 0; e < 4; ++e) fwht4(v[e], v[e + 4], v[e + 8], v[e + 12]);
}

// Pack two f32 -> one u32 of (bf16 lo = a, bf16 hi = b), RNE.
static __device__ __forceinline__ unsigned int pkbf(float a, float b) {
    const __hip_bfloat162 t = __float22bfloat162_rn(make_float2(a, b));
    union { __hip_bfloat162 h; unsigned int u; } cvt;
    cvt.h = t;
    return cvt.u;
}

// LDS: LINEAR layout, word W(j, i) = j*512 + i for chunk-pair j (0..13),
// element i (0..511); word = (bf16 top_j | bf16 bot_{j+14}).
// FWHT writes: lane-consecutive uint4 (2-way, free). Mix reads:
// lane-consecutive b32 (2-way, free). No swizzle needed anywhere.
__global__ __launch_bounds__(512, 8) void quarot_kernel(const float* __restrict__ X,
                                                        float* __restrict__ Y) {
    __shared__ unsigned int s[7168];   // 28 KB
    const int tid = threadIdx.x;
    const int l = tid & 63;
    const int w = tid >> 6;     // wave 0..7
    const int q = l & 31;       // lane within half-wave
    const int h = l >> 5;       // which half
    const int hw = 2 * w + h;   // half-wave id 0..15
    const float s1 = (q & 1) ? -1.0f : 1.0f;
    const float s2 = (q & 2) ? -1.0f : 1.0f;
    const float s4 = (q & 4) ? -1.0f : 1.0f;
    const float s8 = (q & 8) ? -1.0f : 1.0f;
    const float s16 = (q & 16) ? -1.0f : 1.0f;

    const float* __restrict__ xr = X + (size_t)blockIdx.x * HIDDEN;
    float* __restrict__ yr = Y + (size_t)blockIdx.x * HIDDEN;
    const float scale = 1.0f / sqrtf((float)HIDDEN);  // compile-time folded

    // FWHT: half-waves 0..13 own chunk-pair j = hw (chunks j and j+14).
    if (hw < 14) {                     // wave-uniform (wave 7 skips entirely)
        const int j = hw;
        const int baseA = j * 512 + q * 4;
        const int baseB = baseA + 14 * 512;
        float vA[16], vB[16];
        #pragma unroll
        for (int g = 0; g < 4; ++g) {  // 512B contiguous per half-wave instr
            const float4 t = *reinterpret_cast<const float4*>(xr + baseA + g * 128);
            vA[4 * g + 0] = t.x * scale; vA[4 * g + 1] = t.y * scale;
            vA[4 * g + 2] = t.z * scale; vA[4 * g + 3] = t.w * scale;
        }
        #pragma unroll
        for (int g = 0; g < 4; ++g) {
            const float4 t = *reinterpret_cast<const float4*>(xr + baseB + g * 128);
            vB[4 * g + 0] = t.x * scale; vB[4 * g + 1] = t.y * scale;
            vB[4 * g + 2] = t.z * scale; vB[4 * g + 3] = t.w * scale;
        }

        fwht512(vA, s1, s2, s4, s8, s16);
        fwht512(vB, s1, s2, s4, s8, s16);

        // Pack (top, bottom) and write 4x lane-consecutive uint4.
        #pragma unroll
        for (int g = 0; g < 4; ++g) {
            uint4 pw;
            pw.x = pkbf(vA[4 * g + 0], vB[4 * g + 0]);
            pw.y = pkbf(vA[4 * g + 1], vB[4 * g + 1]);
            pw.z = pkbf(vA[4 * g + 2], vB[4 * g + 2]);
            pw.w = pkbf(vA[4 * g + 3], vB[4 * g + 3]);
            *reinterpret_cast<uint4*>(s + j * 512 + g * 128 + q * 4) = pw;
        }
    }

    __syncthreads();

    // ---- Mix: conference-matrix CSE, exactly one column per thread. ----
    {
        const int c = tid;
        float u[14], d[14];
        #pragma unroll
        for (int j = 0; j < 14; ++j) {
            const unsigned int wd = s[j * 512 + c];
            const float top = __uint_as_float(wd << 16);
            const float bot = __uint_as_float(wd & 0xFFFF0000u);
            u[j] = top + bot;
            d[j] = top - bot;
        }
        const float Su = (((u[0] + u[1]) + (u[2] + u[3])) + ((u[4] + u[5]) + (u[6] + u[7]))) +
                         (((u[8] + u[9]) + (u[10] + u[11])) + (u[12] + u[13]));
        const float Sd = (((d[0] + d[1]) + (d[2] + d[3])) + ((d[4] + d[5]) + (d[6] + d[7]))) +
                         (((d[8] + d[9]) + (d[10] + d[11])) + (d[12] + d[13]));
        #pragma unroll
        for (int i = 0; i < 14; ++i) {
            float nu = 0.0f, nd = 0.0f;
            #pragma unroll
            for (int j = 0; j < 14; ++j) {
                if (j != i && HS[i][j] == '-') {  // compile-time folded
                    nu += u[j];
                    nd += d[j];
                }
            }
            const float Cu = fmaf(-2.0f, nu, Su - u[i]);
            const float Cd = fmaf(-2.0f, nd, Sd - d[i]);
            yr[i * 512 + c] = Cu + d[i];
            yr[(i + 14) * 512 + c] = Cd - u[i];
        }
    }
}

extern "C" void kernel_launch(void* const* d_in, const int* in_sizes, int n_in,
                              void* d_out, int out_size, void* d_ws, size_t ws_size,
                              hipStream_t stream) {
    const float* X = (const float*)d_in[0];
    float* Y = (float*)d_out;
    const int rows = in_sizes[0] / HIDDEN;  // 4096
    quarot_kernel<<<dim3(rows), dim3(512), 0, stream>>>(X, Y);
}

// Round 8
// 74.481 us; speedup vs baseline: 1.2525x; 1.2525x over previous
//
#include <hip/hip_runtime.h>
#include <hip/hip_bf16.h>

#define HIDDEN 14336

// Fixed 28x28 Hadamard sign matrix from the reference (row-major, '+' = +1).
// Structure (verified R2): H28 = [[C+I, C-I],[C-I, -(C+I)]], C = 14x14
// zero-diag conference matrix, C[i][j] = HS[i][j] for i,j<14, i!=j.
constexpr char HS[28][29] = {
    "++++++++++++++-+++++++++++++",
    "+++-++----++-++-+-++----++-+",
    "++++-++----++-++-+-++----++-",
    "+-+++-++----+++-+-+-++----++",
    "++-+++-++----+++-+-+-++----+",
    "+++-+++-++----+++-+-+-++----",
    "+-++-+++-++---+-++-+-+-++---",
    "+--++-+++-++--+--++-+-+-++--",
    "+---++-+++-++-+---++-+-+-++-",
    "+----++-+++-+++----++-+-+-++",
    "++----++-+++-+++----++-+-+-+",
    "+++----++-+++-+++----++-+-+-",
    "+-++----++-++++-++----++-+-+",
    "++-++----++-++++-++----++-+-",
    "-+++++++++++++--------------",
    "+-+-++----++-+---+--++++--+-",
    "++-+-++----++-----+--++++--+",
    "+-+-+-++----++-+---+--++++--",
    "++-+-+-++----+--+---+--++++-",
    "+++-+-+-++-------+---+--++++",
    "+-++-+-+-++----+--+---+--+++",
    "+--++-+-+-++---++--+---+--++",
    "+---++-+-+-++--+++--+---+--+",
    "+----++-+-+-++-++++--+---+--",
    "++----++-+-+-+--++++--+---+-",
    "+++----++-+-+----++++--+---+",
    "+-++----++-+-+-+--++++--+---",
    "++-++----++-+---+--++++--+--",
};

// In-lane FWHT over 16 registers (bits 0..3 of the element index).
static __device__ __forceinline__ void fwht16(float (&v)[16]) {
    #pragma unroll
    for (int h = 1; h < 16; h <<= 1) {
        #pragma unroll
        for (int i = 0; i < 16; ++i) {
            if ((i & h) == 0) {
                const float a = v[i], b = v[i | h];
                v[i] = a + b;
                v[i | h] = a - b;
            }
        }
    }
}

// Cross-lane butterfly: out_l = v_{l^m} + sgn_l * v_l, sgn in a VGPR (+-1.0).
// XOR-1 / XOR-2 partners via DPP quad_perm (VALU pipe).
template <int CTRL>
static __device__ __forceinline__ float bfly_dpp(float x, float sgn) {
    const int fi = __float_as_int(x);
    const int p = __builtin_amdgcn_update_dpp(fi, fi, CTRL, 0xF, 0xF, false);
    return fmaf(sgn, x, __int_as_float(p));
}

// XOR-4 / 8 / 16 partners via ds_swizzle BitMode (intra-32-lane).
template <int PAT>
static __device__ __forceinline__ float bfly_swz(float x, float sgn) {
    const int p = __builtin_amdgcn_ds_swizzle(__float_as_int(x), PAT);
    return fmaf(sgn, x, __int_as_float(p));
}

// FWHT32 across the 32-lane half (bits 4..8 of the element index).
static __device__ __forceinline__ void fwht_cross32(float (&v)[16], float s1, float s2,
                                                    float s4, float s8, float s16) {
    #pragma unroll
    for (int k = 0; k < 16; ++k) v[k] = bfly_dpp<0xB1>(v[k], s1);   // quad_perm [1,0,3,2]
    #pragma unroll
    for (int k = 0; k < 16; ++k) v[k] = bfly_dpp<0x4E>(v[k], s2);   // quad_perm [2,3,0,1]
    #pragma unroll
    for (int k = 0; k < 16; ++k) v[k] = bfly_swz<0x101F>(v[k], s4);  // xor 4
    #pragma unroll
    for (int k = 0; k < 16; ++k) v[k] = bfly_swz<0x201F>(v[k], s8);  // xor 8
    #pragma unroll
    for (int k = 0; k < 16; ++k) v[k] = bfly_swz<0x401F>(v[k], s16); // xor 16
}

// Pack two f32 -> one u32 of (bf16 lo = a, bf16 hi = b), RNE.
static __device__ __forceinline__ unsigned int pkbf(float a, float b) {
    const __hip_bfloat162 t = __float22bfloat162_rn(make_float2(a, b));
    union { __hip_bfloat162 h; unsigned int u; } cvt;
    cvt.h = t;
    return cvt.u;
}

// LDS layout: word W(j, c) = j*512 + (c & ~15) + 4*(((c>>2)&3) ^ ((c>>5)&3)) + (c&3)
// for chunk-pair j (0..13) and column c (0..511); word = (bf16 top_j | bf16 bot_{j+14}).
static __device__ __forceinline__ int colpart(int c) {
    return (c & ~15) + 4 * (((c >> 2) & 3) ^ ((c >> 5) & 3)) + (c & 3);
}

// Conference-matrix-CSE mix for one column c. Y stores are NON-TEMPORAL:
// Y is write-once/never-re-read; keeping it out of L3 preserves X residency.
static __device__ __forceinline__ void mix_col(const unsigned int* __restrict__ s, int cp,
                                               float* __restrict__ yr, int c) {
    float u[14], d[14];
    #pragma unroll
    for (int j = 0; j < 14; ++j) {
        const unsigned int wd = s[j * 512 + cp];
        const float top = __uint_as_float(wd << 16);
        const float bot = __uint_as_float(wd & 0xFFFF0000u);
        u[j] = top + bot;
        d[j] = top - bot;
    }
    const float Su = (((u[0] + u[1]) + (u[2] + u[3])) + ((u[4] + u[5]) + (u[6] + u[7]))) +
                     (((u[8] + u[9]) + (u[10] + u[11])) + (u[12] + u[13]));
    const float Sd = (((d[0] + d[1]) + (d[2] + d[3])) + ((d[4] + d[5]) + (d[6] + d[7]))) +
                     (((d[8] + d[9]) + (d[10] + d[11])) + (d[12] + d[13]));
    #pragma unroll
    for (int i = 0; i < 14; ++i) {
        float nu = 0.0f, nd = 0.0f;
        #pragma unroll
        for (int j = 0; j < 14; ++j) {
            if (j != i && HS[i][j] == '-') {  // compile-time folded
                nu += u[j];
                nd += d[j];
            }
        }
        const float Cu = fmaf(-2.0f, nu, Su - u[i]);
        const float Cd = fmaf(-2.0f, nd, Sd - d[i]);
        __builtin_nontemporal_store(Cu + d[i], &yr[i * 512 + c]);
        __builtin_nontemporal_store(Cd - u[i], &yr[(i + 14) * 512 + c]);
    }
}

__global__ __launch_bounds__(448, 8) void quarot_kernel(const float* __restrict__ X,
                                                        float* __restrict__ Y) {
    __shared__ unsigned int s[7168];   // 28 KB -> 4 blocks/CU (28 waves)
    const int tid = threadIdx.x;
    const int l = tid & 63;
    const int w = tid >> 6;     // wave 0..6
    const int q = l & 31;       // lane within half-wave
    const int h = l >> 5;       // which half
    const float s1 = (q & 1) ? -1.0f : 1.0f;
    const float s2 = (q & 2) ? -1.0f : 1.0f;
    const float s4 = (q & 4) ? -1.0f : 1.0f;
    const float s8 = (q & 8) ? -1.0f : 1.0f;
    const float s16 = (q & 16) ? -1.0f : 1.0f;

    const float* __restrict__ xr = X + (size_t)blockIdx.x * HIDDEN;
    float* __restrict__ yr = Y + (size_t)blockIdx.x * HIDDEN;
    const float scale = 1.0f / sqrtf((float)HIDDEN);  // compile-time folded

    // Chunk-pair ownership: half-wave (w,h) owns pair j = w + 7h, i.e. chunks
    // j (top) and j+14 (bottom) -> u/d pairs are lane-local after FWHT.
    const int j = w + 7 * h;
    const int offA = j * 512 + q * 16;
    const int offB = offA + 14 * 512;

    float vA[16], vB[16];
    #pragma unroll
    for (int g = 0; g < 4; ++g) {
        const float4 t = *reinterpret_cast<const float4*>(xr + offA + 4 * g);
        vA[4 * g + 0] = t.x * scale; vA[4 * g + 1] = t.y * scale;
        vA[4 * g + 2] = t.z * scale; vA[4 * g + 3] = t.w * scale;
    }
    #pragma unroll
    for (int g = 0; g < 4; ++g) {
        const float4 t = *reinterpret_cast<const float4*>(xr + offB + 4 * g);
        vB[4 * g + 0] = t.x * scale; vB[4 * g + 1] = t.y * scale;
        vB[4 * g + 2] = t.z * scale; vB[4 * g + 3] = t.w * scale;
    }

    fwht16(vA);
    fwht_cross32(vA, s1, s2, s4, s8, s16);
    fwht16(vB);
    fwht_cross32(vB, s1, s2, s4, s8, s16);

    // Pack (top, bottom) pairs and write 4x swizzled b128.
    {
        const int base = j * 512 + 16 * q;
        const int rot = (q >> 1) & 3;
        #pragma unroll
        for (int m = 0; m < 4; ++m) {
            const int slot = m ^ rot;
            uint4 pw;
            pw.x = pkbf(vA[4 * m + 0], vB[4 * m + 0]);
            pw.y = pkbf(vA[4 * m + 1], vB[4 * m + 1]);
            pw.z = pkbf(vA[4 * m + 2], vB[4 * m + 2]);
            pw.w = pkbf(vA[4 * m + 3], vB[4 * m + 3]);
            *reinterpret_cast<uint4*>(s + base + 4 * slot) = pw;
        }
    }

    __syncthreads();

    // ---- Mix phase: 448 cols + 64 extra on wave 0; coalesced NT stores. ----
    mix_col(s, colpart(tid), yr, tid);
    if (tid < 64) {
        const int c1 = tid + 448;
        mix_col(s, colpart(c1), yr, c1);
    }
}

extern "C" void kernel_launch(void* const* d_in, const int* in_sizes, int n_in,
                              void* d_out, int out_size, void* d_ws, size_t ws_size,
                              hipStream_t stream) {
    const float* X = (const float*)d_in[0];
    float* Y = (float*)d_out;
    const int rows = in_sizes[0] / HIDDEN;  // 4096
    quarot_kernel<<<dim3(rows), dim3(448), 0, stream>>>(X, Y);
}